// Round 3
// baseline (3105.082 us; speedup 1.0000x reference)
//
#include <hip/hip_runtime.h>
#include <math.h>

#define NB 4
#define NV 8
#define NC 32
#define NG 65536
#define IMGW 256

static constexpr long long STACKED_ELEMS = (long long)NB * NV * NG * NC; // 67108864

// ---------------- ws layout ----------------
// At      : 256 f32                     @ 0          (1 KB)
// cnt     : 32 * 65536 u32              @ 1 KB       (8 MB)   bin counts per (b,i)
// cursor  : 32 * 65536 u32              @ +8 MB      (8 MB)   scan -> fill cursor -> bin ends
// pixarr  : [b][i][j][g] u16            @ +8 MB      (32 MB)  precomputed pixels
// sorted  : [b][i][slot] u32 (1<<19 ea) @ +32 MB     (64 MB)  payload (j<<16)|g
static constexpr size_t OFF_AT   = 0;
static constexpr size_t OFF_CNT  = 1024;
static constexpr size_t OFF_CUR  = OFF_CNT + (size_t)32 * 65536 * 4;
static constexpr size_t OFF_PIX  = OFF_CUR + (size_t)32 * 65536 * 4;
static constexpr size_t OFF_SORT = OFF_PIX + (size_t)NB * NV * NV * NG * 2;

// ---------------- adjacency: A (to d_out tail) and A_tilde (to ws) ----------------
__global__ __launch_bounds__(256) void adj_kernel(const float* __restrict__ ext,
                                                  float* __restrict__ A_out,
                                                  float* __restrict__ At_out)
{
    __shared__ float ctr[NB * NV][3];
    __shared__ float Dsh[NB * NV * NV];
    int t = threadIdx.x;
    if (t < NB * NV) {
        const float* E = ext + t * 16;
        #pragma unroll
        for (int i = 0; i < 3; i++) {
            float s = E[0 * 4 + i] * E[0 * 4 + 3]
                    + E[1 * 4 + i] * E[1 * 4 + 3]
                    + E[2 * 4 + i] * E[2 * 4 + 3];
            ctr[t][i] = -s;
        }
    }
    __syncthreads();
    {
        int b = t >> 6, i = (t >> 3) & 7, j = t & 7;
        float dx = ctr[b * 8 + i][0] - ctr[b * 8 + j][0];
        float dy = ctr[b * 8 + i][1] - ctr[b * 8 + j][1];
        float dz = ctr[b * 8 + i][2] - ctr[b * 8 + j][2];
        Dsh[t] = dx * dx + dy * dy + dz * dz;
    }
    __syncthreads();
    if (t < NB * NV) {
        int ri = t & 7;
        const float* drow = &Dsh[t * 8];
        bool chosen[8] = {false, false, false, false, false, false, false, false};
        for (int n = 0; n < 3; n++) {
            int best = -1; float bs = -3.0e38f;
            for (int j2 = 0; j2 < 8; j2++) {
                if (j2 == ri || chosen[j2]) continue;
                float s = -drow[j2];
                if (s > bs) { bs = s; best = j2; }
            }
            chosen[best] = true;
        }
        float row[8]; float deg = 0.f;
        #pragma unroll
        for (int j2 = 0; j2 < 8; j2++) {
            float a = 0.f;
            if (j2 == ri)        a = 1.0f;
            else if (chosen[j2]) a = 1.0f / (1.0f + sqrtf(drow[j2] + 1e-6f));
            row[j2] = a; deg += a;
        }
        float dn = deg + (deg == 0.f ? 1.f : 0.f);
        #pragma unroll
        for (int j2 = 0; j2 < 8; j2++) {
            A_out[t * 8 + j2]  = row[j2];
            At_out[t * 8 + j2] = row[j2] / dn;
        }
    }
}

// ---------------- A1: pixel precompute + histogram ----------------
// tid enumerates [b][j][i][g] (xy layout) for coalesced float2 reads.
__global__ __launch_bounds__(256) void a1_hist(const float2* __restrict__ xy,
                                               unsigned short* __restrict__ pixarr,
                                               unsigned int* __restrict__ cnt)
{
    unsigned int tid = blockIdx.x * 256 + threadIdx.x; // 16,777,216 total
    unsigned int g = tid & 0xFFFFu;
    unsigned int i = (tid >> 16) & 7u;
    unsigned int j = (tid >> 19) & 7u;
    unsigned int b = tid >> 22;
    float2 p = xy[tid];
    float px = fminf(fmaxf(rintf(p.x), 0.f), (float)(IMGW - 1));
    float py = fminf(fmaxf(rintf(p.y), 0.f), (float)(IMGW - 1));
    unsigned int pix = (unsigned int)py * IMGW + (unsigned int)px;
    unsigned int bi = (b << 3) | i;
    pixarr[(((bi << 3) | j) << 16) | g] = (unsigned short)pix; // [b][i][j][g]
    atomicAdd(&cnt[(bi << 16) | pix], 1u);
}

// ---------------- scan: exclusive prefix per (b,i), writes cursor=starts ----------------
__global__ __launch_bounds__(1024) void a_scan(const unsigned int* __restrict__ cnt,
                                               unsigned int* __restrict__ cursor)
{
    __shared__ unsigned int lds[1024];
    int bi = blockIdx.x; // 0..31
    const unsigned int* c = cnt + ((size_t)bi << 16);
    unsigned int* cu = cursor + ((size_t)bi << 16);
    int t = threadIdx.x;
    unsigned int s = 0;
    #pragma unroll 8
    for (int k = 0; k < 64; k++) s += c[t * 64 + k];
    lds[t] = s;
    __syncthreads();
    for (int off = 1; off < 1024; off <<= 1) {
        unsigned int v = (t >= off) ? lds[t - off] : 0u;
        __syncthreads();
        lds[t] += v;
        __syncthreads();
    }
    unsigned int run = lds[t] - s; // exclusive base for this thread's 64-chunk
    for (int k = 0; k < 64; k++) {
        unsigned int cv = c[t * 64 + k];
        cu[t * 64 + k] = run;
        run += cv;
    }
}

// ---------------- A2: fill sorted payload arrays ----------------
// tid enumerates [b][i][j][g] for coalesced pixarr reads.
__global__ __launch_bounds__(256) void a2_fill(const unsigned short* __restrict__ pixarr,
                                               unsigned int* __restrict__ cursor,
                                               unsigned int* __restrict__ sorted)
{
    unsigned int tid = blockIdx.x * 256 + threadIdx.x;
    unsigned int g = tid & 0xFFFFu;
    unsigned int j = (tid >> 16) & 7u;
    unsigned int bi = tid >> 19; // (b<<3)|i
    unsigned int pix = pixarr[tid];
    unsigned int slot = atomicAdd(&cursor[(bi << 16) | pix], 1u);
    sorted[((size_t)bi << 19) + slot] = (j << 16) | g;
}

// ---------------- B: per-output-row gather-accumulate + deferred linear ----------------
// 32-lane group per output row (b,i,g); lane c owns channel c.
__global__ __launch_bounds__(256) void b_gather(
    const float* __restrict__ feat,            // raw features (B,V,G,C)
    const unsigned short* __restrict__ pixarr, // [b][i][j][g]
    const unsigned int* __restrict__ cursor,   // bin ends after a2_fill
    const unsigned int* __restrict__ cnt,      // bin counts
    const unsigned int* __restrict__ sorted,   // payloads per (b,i)
    const float* __restrict__ Wlin,
    const float* __restrict__ blin,
    const float* __restrict__ At,
    float* __restrict__ out)
{
    __shared__ float At_s[NB * NV * NV];
    int t = threadIdx.x;
    At_s[t] = At[t];
    __syncthreads();
    int c = t & 31;
    int grp = t >> 5;
    float wcol[NC];
    #pragma unroll
    for (int k = 0; k < NC; k++) wcol[k] = Wlin[k * NC + c];
    float bias = blin[c];

    unsigned int r = blockIdx.x * 8 + grp; // row id over 2,097,152 = [b][i][g]
    unsigned int g = r & 0xFFFFu;
    unsigned int bi = r >> 16; // (b<<3)|i
    unsigned int i = bi & 7u;
    unsigned int b = bi >> 3;
    unsigned int pix = pixarr[(((bi << 3) | i) << 16) | g]; // diag [b][i][i][g]
    unsigned int end = cursor[(bi << 16) | pix];
    unsigned int count = cnt[(bi << 16) | pix];
    unsigned int start = end - count;
    const unsigned int* pl = sorted + ((size_t)bi << 19);

    float acc = 0.f, wsum = 0.f;
    for (unsigned int k = start; k < end; k++) {
        unsigned int p = pl[k];
        unsigned int j = p >> 16;
        unsigned int gs = p & 0xFFFFu;
        float w = At_s[(bi << 3) | j];
        float fv = feat[((((size_t)((b << 3) | j)) << 16) | gs) * NC + c];
        acc = fmaf(w, fv, acc);
        wsum += w;
    }
    // out[c] = sum_k acc(lane k) * W[k][c] + bias * wsum
    float o = bias * wsum;
    #pragma unroll
    for (int k = 0; k < NC; k++)
        o = fmaf(__shfl(acc, k, 32), wcol[k], o);
    out[(((size_t)bi << 16) | g) * NC + c] = o;
}

extern "C" void kernel_launch(void* const* d_in, const int* in_sizes, int n_in,
                              void* d_out, int out_size, void* d_ws, size_t ws_size,
                              hipStream_t stream)
{
    const float* features = (const float*)d_in[0];
    const float* xy       = (const float*)d_in[1];
    const float* ext      = (const float*)d_in[2];
    const float* Wlin     = (const float*)d_in[3];
    const float* blin     = (const float*)d_in[4];
    float* out = (float*)d_out;

    char* ws = (char*)d_ws;
    float*          At     = (float*)(ws + OFF_AT);
    unsigned int*   cnt    = (unsigned int*)(ws + OFF_CNT);
    unsigned int*   cursor = (unsigned int*)(ws + OFF_CUR);
    unsigned short* pixarr = (unsigned short*)(ws + OFF_PIX);
    unsigned int*   sorted = (unsigned int*)(ws + OFF_SORT);

    adj_kernel<<<1, 256, 0, stream>>>(ext, out + STACKED_ELEMS, At);

    hipMemsetAsync(cnt, 0, (size_t)32 * 65536 * 4, stream);

    const int nsrc_blocks = (NB * NV * NV * NG) / 256; // 65536
    a1_hist<<<nsrc_blocks, 256, 0, stream>>>((const float2*)xy, pixarr, cnt);
    a_scan<<<32, 1024, 0, stream>>>(cnt, cursor);
    a2_fill<<<nsrc_blocks, 256, 0, stream>>>(pixarr, cursor, sorted);

    const int nrows_blocks = (NB * NV * NG) / 8; // 262144 blocks, 8 rows each
    b_gather<<<nrows_blocks, 256, 0, stream>>>(features, pixarr, cursor, cnt, sorted,
                                               Wlin, blin, At, out);
}

// Round 4
// 3061.018 us; speedup vs baseline: 1.0144x; 1.0144x over previous
//
#include <hip/hip_runtime.h>
#include <math.h>

#define NB 4
#define NV 8
#define NC 32
#define NG 65536
#define IMGW 256

static constexpr long long STACKED_ELEMS = (long long)NB * NV * NG * NC; // 67108864

// ---------------- ws layout ----------------
// At      : 256 f32                     @ 0          (1 KB)
// cnt     : 32 * 65536 u32              @ 1 KB       (8 MB)   bin counts per (b,i)
// cursor  : 32 * 65536 u32              @ +8 MB      (8 MB)   scan -> fill cursor -> bin ends
// pixarr  : [b][i][j][g] u16            @ +8 MB      (32 MB)  precomputed pixels
// sorted  : [b][i][slot] u32 (1<<19 ea) @ +32 MB     (64 MB)  payload (j<<16)|g
static constexpr size_t OFF_AT   = 0;
static constexpr size_t OFF_CNT  = 1024;
static constexpr size_t OFF_CUR  = OFF_CNT + (size_t)32 * 65536 * 4;
static constexpr size_t OFF_PIX  = OFF_CUR + (size_t)32 * 65536 * 4;
static constexpr size_t OFF_SORT = OFF_PIX + (size_t)NB * NV * NV * NG * 2;

// ---------------- adjacency: A (to d_out tail) and A_tilde (to ws) ----------------
__global__ __launch_bounds__(256) void adj_kernel(const float* __restrict__ ext,
                                                  float* __restrict__ A_out,
                                                  float* __restrict__ At_out)
{
    __shared__ float ctr[NB * NV][3];
    __shared__ float Dsh[NB * NV * NV];
    int t = threadIdx.x;
    if (t < NB * NV) {
        const float* E = ext + t * 16;
        #pragma unroll
        for (int i = 0; i < 3; i++) {
            float s = E[0 * 4 + i] * E[0 * 4 + 3]
                    + E[1 * 4 + i] * E[1 * 4 + 3]
                    + E[2 * 4 + i] * E[2 * 4 + 3];
            ctr[t][i] = -s;
        }
    }
    __syncthreads();
    {
        int b = t >> 6, i = (t >> 3) & 7, j = t & 7;
        float dx = ctr[b * 8 + i][0] - ctr[b * 8 + j][0];
        float dy = ctr[b * 8 + i][1] - ctr[b * 8 + j][1];
        float dz = ctr[b * 8 + i][2] - ctr[b * 8 + j][2];
        Dsh[t] = dx * dx + dy * dy + dz * dz;
    }
    __syncthreads();
    if (t < NB * NV) {
        int ri = t & 7;
        const float* drow = &Dsh[t * 8];
        bool chosen[8] = {false, false, false, false, false, false, false, false};
        for (int n = 0; n < 3; n++) {
            int best = -1; float bs = -3.0e38f;
            for (int j2 = 0; j2 < 8; j2++) {
                if (j2 == ri || chosen[j2]) continue;
                float s = -drow[j2];
                if (s > bs) { bs = s; best = j2; }
            }
            chosen[best] = true;
        }
        float row[8]; float deg = 0.f;
        #pragma unroll
        for (int j2 = 0; j2 < 8; j2++) {
            float a = 0.f;
            if (j2 == ri)        a = 1.0f;
            else if (chosen[j2]) a = 1.0f / (1.0f + sqrtf(drow[j2] + 1e-6f));
            row[j2] = a; deg += a;
        }
        float dn = deg + (deg == 0.f ? 1.f : 0.f);
        #pragma unroll
        for (int j2 = 0; j2 < 8; j2++) {
            A_out[t * 8 + j2]  = row[j2];
            At_out[t * 8 + j2] = row[j2] / dn;
        }
    }
}

// ---------------- A1: pixel precompute + histogram, 4 items/thread ----------------
__global__ __launch_bounds__(256) void a1_hist(const float2* __restrict__ xy,
                                               unsigned short* __restrict__ pixarr,
                                               unsigned int* __restrict__ cnt)
{
    unsigned int base = blockIdx.x * 1024 + threadIdx.x; // 4 chunks of 256
    unsigned int pixv[4];
    #pragma unroll
    for (int k = 0; k < 4; k++) {
        unsigned int tid = base + k * 256;
        float2 p = xy[tid];
        float px = fminf(fmaxf(rintf(p.x), 0.f), (float)(IMGW - 1));
        float py = fminf(fmaxf(rintf(p.y), 0.f), (float)(IMGW - 1));
        pixv[k] = (unsigned int)py * IMGW + (unsigned int)px;
    }
    #pragma unroll
    for (int k = 0; k < 4; k++) {
        unsigned int tid = base + k * 256; // [b][j][i][g]
        unsigned int g = tid & 0xFFFFu;
        unsigned int i = (tid >> 16) & 7u;
        unsigned int j = (tid >> 19) & 7u;
        unsigned int b = tid >> 22;
        unsigned int bi = (b << 3) | i;
        pixarr[(((bi << 3) | j) << 16) | g] = (unsigned short)pixv[k]; // [b][i][j][g]
        atomicAdd(&cnt[(bi << 16) | pixv[k]], 1u);
    }
}

// ---------------- scan: exclusive prefix per (b,i), writes cursor=starts ----------------
__global__ __launch_bounds__(1024) void a_scan(const unsigned int* __restrict__ cnt,
                                               unsigned int* __restrict__ cursor)
{
    __shared__ unsigned int lds[1024];
    int bi = blockIdx.x; // 0..31
    const unsigned int* c = cnt + ((size_t)bi << 16);
    unsigned int* cu = cursor + ((size_t)bi << 16);
    int t = threadIdx.x;
    unsigned int s = 0;
    #pragma unroll 8
    for (int k = 0; k < 64; k++) s += c[t * 64 + k];
    lds[t] = s;
    __syncthreads();
    for (int off = 1; off < 1024; off <<= 1) {
        unsigned int v = (t >= off) ? lds[t - off] : 0u;
        __syncthreads();
        lds[t] += v;
        __syncthreads();
    }
    unsigned int run = lds[t] - s; // exclusive base for this thread's 64-chunk
    for (int k = 0; k < 64; k++) {
        unsigned int cv = c[t * 64 + k];
        cu[t * 64 + k] = run;
        run += cv;
    }
}

// ---------------- A2: fill sorted payload arrays, 16 items/thread ----------------
// 16 independent fetch-adds in flight per thread -> latency hidden.
__global__ __launch_bounds__(256) void a2_fill(const unsigned short* __restrict__ pixarr,
                                               unsigned int* __restrict__ cursor,
                                               unsigned int* __restrict__ sorted)
{
    unsigned int base = blockIdx.x * 4096 + threadIdx.x; // 16 chunks of 256
    unsigned int pixv[16];
    unsigned int slot[16];
    #pragma unroll
    for (int k = 0; k < 16; k++)
        pixv[k] = pixarr[base + k * 256];
    #pragma unroll
    for (int k = 0; k < 16; k++) {
        unsigned int tid = base + k * 256; // [b][i][j][g]
        unsigned int bi = tid >> 19;
        slot[k] = atomicAdd(&cursor[(bi << 16) | pixv[k]], 1u);
    }
    #pragma unroll
    for (int k = 0; k < 16; k++) {
        unsigned int tid = base + k * 256;
        unsigned int bi = tid >> 19;
        unsigned int j = (tid >> 16) & 7u;
        sorted[((size_t)bi << 19) + slot[k]] = (j << 16) | (tid & 0xFFFFu);
    }
}

// ---------------- B: per-output-row gather-accumulate + deferred linear ----------------
// 32-lane group per output row (b,i,g); lane c owns channel c.
__global__ __launch_bounds__(256) void b_gather(
    const float* __restrict__ feat,            // raw features (B,V,G,C)
    const unsigned short* __restrict__ pixarr, // [b][i][j][g]
    const unsigned int* __restrict__ cursor,   // bin ends after a2_fill
    const unsigned int* __restrict__ cnt,      // bin counts
    const unsigned int* __restrict__ sorted,   // payloads per (b,i)
    const float* __restrict__ Wlin,
    const float* __restrict__ blin,
    const float* __restrict__ At,
    float* __restrict__ out)
{
    __shared__ float At_s[NB * NV * NV];
    int t = threadIdx.x;
    int c = t & 31;
    int grp = t >> 5;

    // issue row-descriptor loads ASAP (before W-column loads)
    unsigned int r = blockIdx.x * 8 + grp; // row id over 2,097,152 = [b][i][g]
    unsigned int g = r & 0xFFFFu;
    unsigned int bi = r >> 16; // (b<<3)|i
    unsigned int i = bi & 7u;
    unsigned int b = bi >> 3;
    unsigned int pix = pixarr[(((bi << 3) | i) << 16) | g]; // diag [b][i][i][g]

    At_s[t] = At[t];
    float wcol[NC];
    #pragma unroll
    for (int k = 0; k < NC; k++) wcol[k] = Wlin[k * NC + c];
    float bias = blin[c];

    unsigned int end = cursor[(bi << 16) | pix];
    unsigned int count = cnt[(bi << 16) | pix];
    unsigned int start = end - count;
    const unsigned int* pl = sorted + ((size_t)bi << 19);
    const float* featb = feat + (((size_t)b) << (3 + 16)) * NC; // feat[b]
    __syncthreads();

    float acc = 0.f, wsum = 0.f;
    for (unsigned int k = start; k < end; k++) {
        unsigned int p = pl[k];
        unsigned int j = p >> 16;
        unsigned int gs = p & 0xFFFFu;
        float w = At_s[(bi << 3) | j];
        float fv = featb[(((size_t)j << 16) | gs) * NC + c];
        acc = fmaf(w, fv, acc);
        wsum += w;
    }
    // out[c] = sum_k acc(lane k) * W[k][c] + bias * wsum
    float o = bias * wsum;
    #pragma unroll
    for (int k = 0; k < NC; k++)
        o = fmaf(__shfl(acc, k, 32), wcol[k], o);
    out[(((size_t)bi << 16) | g) * NC + c] = o;
}

extern "C" void kernel_launch(void* const* d_in, const int* in_sizes, int n_in,
                              void* d_out, int out_size, void* d_ws, size_t ws_size,
                              hipStream_t stream)
{
    const float* features = (const float*)d_in[0];
    const float* xy       = (const float*)d_in[1];
    const float* ext      = (const float*)d_in[2];
    const float* Wlin     = (const float*)d_in[3];
    const float* blin     = (const float*)d_in[4];
    float* out = (float*)d_out;

    char* ws = (char*)d_ws;
    float*          At     = (float*)(ws + OFF_AT);
    unsigned int*   cnt    = (unsigned int*)(ws + OFF_CNT);
    unsigned int*   cursor = (unsigned int*)(ws + OFF_CUR);
    unsigned short* pixarr = (unsigned short*)(ws + OFF_PIX);
    unsigned int*   sorted = (unsigned int*)(ws + OFF_SORT);

    adj_kernel<<<1, 256, 0, stream>>>(ext, out + STACKED_ELEMS, At);

    hipMemsetAsync(cnt, 0, (size_t)32 * 65536 * 4, stream);

    a1_hist<<<(NB * NV * NV * NG) / 1024, 256, 0, stream>>>((const float2*)xy, pixarr, cnt);
    a_scan<<<32, 1024, 0, stream>>>(cnt, cursor);
    a2_fill<<<(NB * NV * NV * NG) / 4096, 256, 0, stream>>>(pixarr, cursor, sorted);

    const int nrows_blocks = (NB * NV * NG) / 8; // 262144 blocks, 8 rows each
    b_gather<<<nrows_blocks, 256, 0, stream>>>(features, pixarr, cursor, cnt, sorted,
                                               Wlin, blin, At, out);
}

// Round 5
// 1570.522 us; speedup vs baseline: 1.9771x; 1.9490x over previous
//
#include <hip/hip_runtime.h>
#include <math.h>

#define NB 4
#define NV 8
#define NC 32
#define NG 65536
#define IMGW 256
#define NBI 32              // NB*NV
#define RSPLIT 8            // pixel-range split per (b,i)
#define RBINS (NG / RSPLIT) // 8192 bins per range
#define START_STRIDE 65544  // 65536 + sentinel + pad

static constexpr long long STACKED_ELEMS = (long long)NB * NV * NG * NC; // 67108864

// ---------------- ws layout ----------------
// At     : 256 f32                 @ 0
// start  : [bi][65544] u32         @ 4 KB    (8.4 MB)  exclusive prefix + sentinel at [65536]
// cnt    : [bi][65536] u32         @ +8.4 MB (8 MB)
// pixarr : [bi][j][g] u16          @ +16.4MB (32 MB)
// sorted : [bi][slot] u32 (1<<19)  @ +48.4MB (64 MB)   payload m = (j<<16)|g
static constexpr size_t OFF_AT    = 0;
static constexpr size_t OFF_START = 4096;
static constexpr size_t OFF_CNT   = OFF_START + (size_t)NBI * START_STRIDE * 4;
static constexpr size_t OFF_PIX   = OFF_CNT + (size_t)NBI * NG * 4;
static constexpr size_t OFF_SORT  = OFF_PIX + (size_t)NBI * NV * NG * 2;

// ---------------- adjacency ----------------
__global__ __launch_bounds__(256) void adj_kernel(const float* __restrict__ ext,
                                                  float* __restrict__ A_out,
                                                  float* __restrict__ At_out)
{
    __shared__ float ctr[NB * NV][3];
    __shared__ float Dsh[NB * NV * NV];
    int t = threadIdx.x;
    if (t < NB * NV) {
        const float* E = ext + t * 16;
        #pragma unroll
        for (int i = 0; i < 3; i++) {
            float s = E[0 * 4 + i] * E[0 * 4 + 3]
                    + E[1 * 4 + i] * E[1 * 4 + 3]
                    + E[2 * 4 + i] * E[2 * 4 + 3];
            ctr[t][i] = -s;
        }
    }
    __syncthreads();
    {
        int b = t >> 6, i = (t >> 3) & 7, j = t & 7;
        float dx = ctr[b * 8 + i][0] - ctr[b * 8 + j][0];
        float dy = ctr[b * 8 + i][1] - ctr[b * 8 + j][1];
        float dz = ctr[b * 8 + i][2] - ctr[b * 8 + j][2];
        Dsh[t] = dx * dx + dy * dy + dz * dz;
    }
    __syncthreads();
    if (t < NB * NV) {
        int ri = t & 7;
        const float* drow = &Dsh[t * 8];
        bool chosen[8] = {false, false, false, false, false, false, false, false};
        for (int n = 0; n < 3; n++) {
            int best = -1; float bs = -3.0e38f;
            for (int j2 = 0; j2 < 8; j2++) {
                if (j2 == ri || chosen[j2]) continue;
                float s = -drow[j2];
                if (s > bs) { bs = s; best = j2; }
            }
            chosen[best] = true;
        }
        float row[8]; float deg = 0.f;
        #pragma unroll
        for (int j2 = 0; j2 < 8; j2++) {
            float a = 0.f;
            if (j2 == ri)        a = 1.0f;
            else if (chosen[j2]) a = 1.0f / (1.0f + sqrtf(drow[j2] + 1e-6f));
            row[j2] = a; deg += a;
        }
        float dn = deg + (deg == 0.f ? 1.f : 0.f);
        #pragma unroll
        for (int j2 = 0; j2 < 8; j2++) {
            A_out[t * 8 + j2]  = row[j2];
            At_out[t * 8 + j2] = row[j2] / dn;
        }
    }
}

// ---------------- k1: pixel precompute (pure streaming, no atomics) ----------------
__global__ __launch_bounds__(256) void k1_pix(const float2* __restrict__ xy,
                                              unsigned short* __restrict__ pixarr)
{
    unsigned int base = blockIdx.x * 1024 + threadIdx.x; // 4 chunks of 256
    #pragma unroll
    for (int k = 0; k < 4; k++) {
        unsigned int tid = base + k * 256; // [b][j][i][g]
        float2 p = xy[tid];
        float px = fminf(fmaxf(rintf(p.x), 0.f), (float)(IMGW - 1));
        float py = fminf(fmaxf(rintf(p.y), 0.f), (float)(IMGW - 1));
        unsigned int pix = (unsigned int)py * IMGW + (unsigned int)px;
        unsigned int g = tid & 0xFFFFu;
        unsigned int i = (tid >> 16) & 7u;
        unsigned int j = (tid >> 19) & 7u;
        unsigned int b = tid >> 22;
        unsigned int bi = (b << 3) | i;
        pixarr[(((bi << 3) | j) << 16) | g] = (unsigned short)pix; // [bi][j][g]
    }
}

// ---------------- k2: LDS histogram per (bi, pixel-range) ----------------
// 256 blocks x 1024 threads. Each block scans its bi's 512K pixels, counts
// only those in its 8192-bin range. No global atomics: each bin owned by one block.
__global__ __launch_bounds__(1024) void k2_hist(const unsigned short* __restrict__ pixarr,
                                                unsigned int* __restrict__ cnt)
{
    __shared__ unsigned int hist[RBINS]; // 32 KB
    int t = threadIdx.x;
    unsigned int bi = blockIdx.x >> 3;
    unsigned int r  = blockIdx.x & 7u;
    unsigned int r0 = r * RBINS;
    for (int k = t; k < RBINS; k += 1024) hist[k] = 0;
    __syncthreads();
    const uint4* src = (const uint4*)(pixarr + ((size_t)bi << 19)); // 64K uint4
    for (int it = 0; it < 64; it++) {
        uint4 v = src[t + it * 1024];
        const unsigned int* vw = (const unsigned int*)&v;
        #pragma unroll
        for (int h = 0; h < 4; h++) {
            unsigned int w = vw[h];
            unsigned int p0 = (w & 0xFFFFu) - r0;
            unsigned int p1 = (w >> 16) - r0;
            if (p0 < RBINS) atomicAdd(&hist[p0], 1u);
            if (p1 < RBINS) atomicAdd(&hist[p1], 1u);
        }
    }
    __syncthreads();
    unsigned int* dst = cnt + ((size_t)bi << 16) + r0;
    for (int k = t; k < RBINS; k += 1024) dst[k] = hist[k];
}

// ---------------- k3: exclusive scan per bi -> start[] + sentinel ----------------
__global__ __launch_bounds__(1024) void k3_scan(const unsigned int* __restrict__ cnt,
                                                unsigned int* __restrict__ start)
{
    __shared__ unsigned int lds[1024];
    int bi = blockIdx.x;
    const unsigned int* c = cnt + ((size_t)bi << 16);
    unsigned int* st = start + (size_t)bi * START_STRIDE;
    int t = threadIdx.x;
    unsigned int s = 0;
    for (int k = 0; k < 64; k++) s += c[t * 64 + k];
    lds[t] = s;
    __syncthreads();
    for (int off = 1; off < 1024; off <<= 1) {
        unsigned int v = (t >= off) ? lds[t - off] : 0u;
        __syncthreads();
        lds[t] += v;
        __syncthreads();
    }
    unsigned int run = lds[t] - s;
    for (int k = 0; k < 64; k++) {
        unsigned int cv = c[t * 64 + k];
        st[t * 64 + k] = run;
        run += cv;
    }
    if (t == 1023) st[NG] = run; // sentinel = 512K
}

// ---------------- k4: counting-sort fill via LDS cursors (no global atomics) ----------------
__global__ __launch_bounds__(1024) void k4_fill(const unsigned short* __restrict__ pixarr,
                                                const unsigned int* __restrict__ start,
                                                unsigned int* __restrict__ sorted)
{
    __shared__ unsigned int cur[RBINS]; // 32 KB, init = absolute start
    int t = threadIdx.x;
    unsigned int bi = blockIdx.x >> 3;
    unsigned int r  = blockIdx.x & 7u;
    unsigned int r0 = r * RBINS;
    const unsigned int* st = start + (size_t)bi * START_STRIDE + r0;
    for (int k = t; k < RBINS; k += 1024) cur[k] = st[k];
    __syncthreads();
    const uint4* src = (const uint4*)(pixarr + ((size_t)bi << 19));
    unsigned int* dstbase = sorted + ((size_t)bi << 19);
    for (int it = 0; it < 64; it++) {
        unsigned int m0 = (t + it * 1024) * 8;
        uint4 v = src[t + it * 1024];
        const unsigned int* vw = (const unsigned int*)&v;
        #pragma unroll
        for (int h = 0; h < 8; h++) {
            unsigned int w = vw[h >> 1];
            unsigned int pv = ((h & 1) ? (w >> 16) : (w & 0xFFFFu)) - r0;
            if (pv < RBINS) {
                unsigned int slot = atomicAdd(&cur[pv], 1u); // LDS atomic
                dstbase[slot] = m0 + h; // payload m = (j<<16)|g
            }
        }
    }
}

// ---------------- b_gather: per-output-row accumulate + deferred linear ----------------
__global__ __launch_bounds__(256) void b_gather(
    const float* __restrict__ feat,
    const unsigned short* __restrict__ pixarr,
    const unsigned int* __restrict__ start,
    const unsigned int* __restrict__ sorted,
    const float* __restrict__ Wlin,
    const float* __restrict__ blin,
    const float* __restrict__ At,
    float* __restrict__ out)
{
    __shared__ float At_s[NB * NV * NV];
    int t = threadIdx.x;
    int c = t & 31;
    int grp = t >> 5;

    unsigned int rrow = blockIdx.x * 8 + grp; // [bi][g]
    unsigned int g = rrow & 0xFFFFu;
    unsigned int bi = rrow >> 16;
    unsigned int i = bi & 7u;
    unsigned int b = bi >> 3;
    unsigned int pix = pixarr[(((bi << 3) | i) << 16) | g]; // diag pixel

    At_s[t] = At[t];
    float wcol[NC];
    #pragma unroll
    for (int k = 0; k < NC; k++) wcol[k] = Wlin[k * NC + c];
    float bias = blin[c];

    const unsigned int* st = start + (size_t)bi * START_STRIDE;
    unsigned int s0 = st[pix];
    unsigned int e0 = st[pix + 1];
    const unsigned int* pl = sorted + ((size_t)bi << 19);
    const float* featb = feat + (((size_t)b) << 19) * NC; // feat[b]
    __syncthreads();

    float acc = 0.f, wsum = 0.f;
    for (unsigned int k = s0; k < e0; k++) {
        unsigned int p = pl[k];
        unsigned int j = p >> 16;
        unsigned int gs = p & 0xFFFFu;
        float w = At_s[(bi << 3) | j];
        float fv = featb[(((size_t)j << 16) | gs) * NC + c];
        acc = fmaf(w, fv, acc);
        wsum += w;
    }
    float o = bias * wsum;
    #pragma unroll
    for (int k = 0; k < NC; k++)
        o = fmaf(__shfl(acc, k, 32), wcol[k], o);
    out[(((size_t)bi << 16) | g) * NC + c] = o;
}

extern "C" void kernel_launch(void* const* d_in, const int* in_sizes, int n_in,
                              void* d_out, int out_size, void* d_ws, size_t ws_size,
                              hipStream_t stream)
{
    const float* features = (const float*)d_in[0];
    const float* xy       = (const float*)d_in[1];
    const float* ext      = (const float*)d_in[2];
    const float* Wlin     = (const float*)d_in[3];
    const float* blin     = (const float*)d_in[4];
    float* out = (float*)d_out;

    char* ws = (char*)d_ws;
    float*          At     = (float*)(ws + OFF_AT);
    unsigned int*   start  = (unsigned int*)(ws + OFF_START);
    unsigned int*   cnt    = (unsigned int*)(ws + OFF_CNT);
    unsigned short* pixarr = (unsigned short*)(ws + OFF_PIX);
    unsigned int*   sorted = (unsigned int*)(ws + OFF_SORT);

    adj_kernel<<<1, 256, 0, stream>>>(ext, out + STACKED_ELEMS, At);

    k1_pix<<<(NB * NV * NV * NG) / 1024, 256, 0, stream>>>((const float2*)xy, pixarr);
    k2_hist<<<NBI * RSPLIT, 1024, 0, stream>>>(pixarr, cnt);
    k3_scan<<<NBI, 1024, 0, stream>>>(cnt, start);
    k4_fill<<<NBI * RSPLIT, 1024, 0, stream>>>(pixarr, start, sorted);

    const int nrows_blocks = (NB * NV * NG) / 8;
    b_gather<<<nrows_blocks, 256, 0, stream>>>(features, pixarr, start, sorted,
                                               Wlin, blin, At, out);
}

// Round 7
// 991.116 us; speedup vs baseline: 3.1329x; 1.5846x over previous
//
#include <hip/hip_runtime.h>
#include <math.h>

#define NB 4
#define NV 8
#define NC 32
#define NG 65536
#define IMGW 256
#define NBI 32              // NB*NV
#define RSPLIT 8            // pixel-range split per (b,i)
#define RBINS (NG / RSPLIT) // 8192 bins per range
#define START_STRIDE 65544  // 65536 + sentinel + pad

static constexpr long long STACKED_ELEMS = (long long)NB * NV * NG * NC; // 67108864

// ---------------- ws layout ----------------
// At     : 256 f32                 @ 0
// start  : [bi][65544] u32         @ 4 KB    (8.4 MB)  exclusive prefix + sentinel at [65536]
// cnt    : [bi][65536] u32         @ +8.4 MB (8 MB)
// pixarr : [bi][j][g] u16          @ +16.4MB (32 MB)
// sorted : [bi][slot] u32 (1<<19)  @ +48.4MB (64 MB)   payload m = (j<<16)|g
static constexpr size_t OFF_AT    = 0;
static constexpr size_t OFF_START = 4096;
static constexpr size_t OFF_CNT   = OFF_START + (size_t)NBI * START_STRIDE * 4;
static constexpr size_t OFF_PIX   = OFF_CNT + (size_t)NBI * NG * 4;
static constexpr size_t OFF_SORT  = OFF_PIX + (size_t)NBI * NV * NG * 2;

// ---------------- adjacency ----------------
__global__ __launch_bounds__(256) void adj_kernel(const float* __restrict__ ext,
                                                  float* __restrict__ A_out,
                                                  float* __restrict__ At_out)
{
    __shared__ float ctr[NB * NV][3];
    __shared__ float Dsh[NB * NV * NV];
    int t = threadIdx.x;
    if (t < NB * NV) {
        const float* E = ext + t * 16;
        #pragma unroll
        for (int i = 0; i < 3; i++) {
            float s = E[0 * 4 + i] * E[0 * 4 + 3]
                    + E[1 * 4 + i] * E[1 * 4 + 3]
                    + E[2 * 4 + i] * E[2 * 4 + 3];
            ctr[t][i] = -s;
        }
    }
    __syncthreads();
    {
        int b = t >> 6, i = (t >> 3) & 7, j = t & 7;
        float dx = ctr[b * 8 + i][0] - ctr[b * 8 + j][0];
        float dy = ctr[b * 8 + i][1] - ctr[b * 8 + j][1];
        float dz = ctr[b * 8 + i][2] - ctr[b * 8 + j][2];
        Dsh[t] = dx * dx + dy * dy + dz * dz;
    }
    __syncthreads();
    if (t < NB * NV) {
        int ri = t & 7;
        const float* drow = &Dsh[t * 8];
        bool chosen[8] = {false, false, false, false, false, false, false, false};
        for (int n = 0; n < 3; n++) {
            int best = -1; float bs = -3.0e38f;
            for (int j2 = 0; j2 < 8; j2++) {
                if (j2 == ri || chosen[j2]) continue;
                float s = -drow[j2];
                if (s > bs) { bs = s; best = j2; }
            }
            chosen[best] = true;
        }
        float row[8]; float deg = 0.f;
        #pragma unroll
        for (int j2 = 0; j2 < 8; j2++) {
            float a = 0.f;
            if (j2 == ri)        a = 1.0f;
            else if (chosen[j2]) a = 1.0f / (1.0f + sqrtf(drow[j2] + 1e-6f));
            row[j2] = a; deg += a;
        }
        float dn = deg + (deg == 0.f ? 1.f : 0.f);
        #pragma unroll
        for (int j2 = 0; j2 < 8; j2++) {
            A_out[t * 8 + j2]  = row[j2];
            At_out[t * 8 + j2] = row[j2] / dn;
        }
    }
}

// ---------------- k1: pixel precompute (pure streaming, no atomics) ----------------
__global__ __launch_bounds__(256) void k1_pix(const float2* __restrict__ xy,
                                              unsigned short* __restrict__ pixarr)
{
    unsigned int base = blockIdx.x * 1024 + threadIdx.x; // 4 chunks of 256
    #pragma unroll
    for (int k = 0; k < 4; k++) {
        unsigned int tid = base + k * 256; // [b][j][i][g]
        float2 p = xy[tid];
        float px = fminf(fmaxf(rintf(p.x), 0.f), (float)(IMGW - 1));
        float py = fminf(fmaxf(rintf(p.y), 0.f), (float)(IMGW - 1));
        unsigned int pix = (unsigned int)py * IMGW + (unsigned int)px;
        unsigned int g = tid & 0xFFFFu;
        unsigned int i = (tid >> 16) & 7u;
        unsigned int j = (tid >> 19) & 7u;
        unsigned int b = tid >> 22;
        unsigned int bi = (b << 3) | i;
        pixarr[(((bi << 3) | j) << 16) | g] = (unsigned short)pix; // [bi][j][g]
    }
}

// ---------------- k2: LDS histogram per (bi, pixel-range) ----------------
__global__ __launch_bounds__(1024) void k2_hist(const unsigned short* __restrict__ pixarr,
                                                unsigned int* __restrict__ cnt)
{
    __shared__ unsigned int hist[RBINS]; // 32 KB
    int t = threadIdx.x;
    unsigned int bi = blockIdx.x >> 3;
    unsigned int r  = blockIdx.x & 7u;
    unsigned int r0 = r * RBINS;
    for (int k = t; k < RBINS; k += 1024) hist[k] = 0;
    __syncthreads();
    const uint4* src = (const uint4*)(pixarr + ((size_t)bi << 19)); // 64K uint4
    for (int it = 0; it < 64; it++) {
        uint4 v = src[t + it * 1024];
        const unsigned int* vw = (const unsigned int*)&v;
        #pragma unroll
        for (int h = 0; h < 4; h++) {
            unsigned int w = vw[h];
            unsigned int p0 = (w & 0xFFFFu) - r0;
            unsigned int p1 = (w >> 16) - r0;
            if (p0 < RBINS) atomicAdd(&hist[p0], 1u);
            if (p1 < RBINS) atomicAdd(&hist[p1], 1u);
        }
    }
    __syncthreads();
    unsigned int* dst = cnt + ((size_t)bi << 16) + r0;
    for (int k = t; k < RBINS; k += 1024) dst[k] = hist[k];
}

// ---------------- k3: exclusive scan per bi -> start[] + sentinel ----------------
__global__ __launch_bounds__(1024) void k3_scan(const unsigned int* __restrict__ cnt,
                                                unsigned int* __restrict__ start)
{
    __shared__ unsigned int lds[1024];
    int bi = blockIdx.x;
    const unsigned int* c = cnt + ((size_t)bi << 16);
    unsigned int* st = start + (size_t)bi * START_STRIDE;
    int t = threadIdx.x;
    unsigned int s = 0;
    for (int k = 0; k < 64; k++) s += c[t * 64 + k];
    lds[t] = s;
    __syncthreads();
    for (int off = 1; off < 1024; off <<= 1) {
        unsigned int v = (t >= off) ? lds[t - off] : 0u;
        __syncthreads();
        lds[t] += v;
        __syncthreads();
    }
    unsigned int run = lds[t] - s;
    for (int k = 0; k < 64; k++) {
        unsigned int cv = c[t * 64 + k];
        st[t * 64 + k] = run;
        run += cv;
    }
    if (t == 1023) st[NG] = run; // sentinel = 512K
}

// ---------------- k4: counting-sort fill via LDS cursors (no global atomics) ----------------
__global__ __launch_bounds__(1024) void k4_fill(const unsigned short* __restrict__ pixarr,
                                                const unsigned int* __restrict__ start,
                                                unsigned int* __restrict__ sorted)
{
    __shared__ unsigned int cur[RBINS]; // 32 KB, init = absolute start
    int t = threadIdx.x;
    unsigned int bi = blockIdx.x >> 3;
    unsigned int r  = blockIdx.x & 7u;
    unsigned int r0 = r * RBINS;
    const unsigned int* st = start + (size_t)bi * START_STRIDE + r0;
    for (int k = t; k < RBINS; k += 1024) cur[k] = st[k];
    __syncthreads();
    const uint4* src = (const uint4*)(pixarr + ((size_t)bi << 19));
    unsigned int* dstbase = sorted + ((size_t)bi << 19);
    for (int it = 0; it < 64; it++) {
        unsigned int m0 = (t + it * 1024) * 8;
        uint4 v = src[t + it * 1024];
        const unsigned int* vw = (const unsigned int*)&v;
        #pragma unroll
        for (int h = 0; h < 8; h++) {
            unsigned int w = vw[h >> 1];
            unsigned int pv = ((h & 1) ? (w >> 16) : (w & 0xFFFFu)) - r0;
            if (pv < RBINS) {
                unsigned int slot = atomicAdd(&cur[pv], 1u); // LDS atomic
                dstbase[slot] = m0 + h; // payload m = (j<<16)|g
            }
        }
    }
}

// ---------------- b_gather: 8-wide batched gather + deferred linear ----------------
// 32-lane group per output row (b,i,g); lane c owns channel c.
// Chunks of 8 contributions, unconditional loads, zero-weight padding -> 8
// independent random feat lines in flight per group.
__global__ __launch_bounds__(256) void b_gather(
    const float* __restrict__ feat,
    const unsigned short* __restrict__ pixarr,
    const unsigned int* __restrict__ start,
    const unsigned int* __restrict__ sorted,
    const float* __restrict__ Wlin,
    const float* __restrict__ blin,
    const float* __restrict__ At,
    float* __restrict__ out)
{
    __shared__ float At_s[NB * NV * NV];
    int t = threadIdx.x;
    int c = t & 31;
    int grp = t >> 5;

    unsigned int rrow = blockIdx.x * 8 + grp; // [bi][g]
    unsigned int g = rrow & 0xFFFFu;
    unsigned int bi = rrow >> 16;
    unsigned int i = bi & 7u;
    unsigned int b = bi >> 3;
    unsigned int pix = pixarr[(((bi << 3) | i) << 16) | g]; // diag pixel

    At_s[t] = At[t];

    const unsigned int* st = start + (size_t)bi * START_STRIDE;
    unsigned int s0 = st[pix];
    unsigned int e0 = st[pix + 1];
    const unsigned int* pl = sorted + ((size_t)bi << 19);
    const float* featb = feat + (((size_t)b) << 19) * NC; // feat[b]
    __syncthreads();

    const float* Atrow = &At_s[bi << 3];
    float acc = 0.f, wsum = 0.f;
    for (unsigned int k0 = s0; k0 < e0; k0 += 8) {
        unsigned int pv[8];
        float fv[8];
        float wv[8];
        #pragma unroll
        for (int h = 0; h < 8; h++)
            pv[h] = pl[k0 + h]; // unconditional; pads read garbage (valid mem)
        #pragma unroll
        for (int h = 0; h < 8; h++) {
            unsigned int j = (pv[h] >> 16) & 7u;
            unsigned int gs = pv[h] & 0xFFFFu;
            fv[h] = featb[(((size_t)j << 16) | gs) * NC + c]; // always in-bounds of feat[b]
        }
        #pragma unroll
        for (int h = 0; h < 8; h++) {
            unsigned int j = (pv[h] >> 16) & 7u;
            wv[h] = (k0 + h < e0) ? Atrow[j] : 0.f;
        }
        #pragma unroll
        for (int h = 0; h < 8; h++) {
            acc = fmaf(wv[h], fv[h], acc);
            wsum += wv[h];
        }
    }

    // epilogue: wcol loads sunk here to keep loop register pressure low
    float o;
    {
        float bias = blin[c];
        o = bias * wsum;
        #pragma unroll
        for (int k = 0; k < NC; k++) {
            float wc = Wlin[k * NC + c];
            o = fmaf(__shfl(acc, k, 32), wc, o);
        }
    }
    out[(((size_t)bi << 16) | g) * NC + c] = o;
}

extern "C" void kernel_launch(void* const* d_in, const int* in_sizes, int n_in,
                              void* d_out, int out_size, void* d_ws, size_t ws_size,
                              hipStream_t stream)
{
    const float* features = (const float*)d_in[0];
    const float* xy       = (const float*)d_in[1];
    const float* ext      = (const float*)d_in[2];
    const float* Wlin     = (const float*)d_in[3];
    const float* blin     = (const float*)d_in[4];
    float* out = (float*)d_out;

    char* ws = (char*)d_ws;
    float*          At     = (float*)(ws + OFF_AT);
    unsigned int*   start  = (unsigned int*)(ws + OFF_START);
    unsigned int*   cnt    = (unsigned int*)(ws + OFF_CNT);
    unsigned short* pixarr = (unsigned short*)(ws + OFF_PIX);
    unsigned int*   sorted = (unsigned int*)(ws + OFF_SORT);

    adj_kernel<<<1, 256, 0, stream>>>(ext, out + STACKED_ELEMS, At);

    k1_pix<<<(NB * NV * NV * NG) / 1024, 256, 0, stream>>>((const float2*)xy, pixarr);
    k2_hist<<<NBI * RSPLIT, 1024, 0, stream>>>(pixarr, cnt);
    k3_scan<<<NBI, 1024, 0, stream>>>(cnt, start);
    k4_fill<<<NBI * RSPLIT, 1024, 0, stream>>>(pixarr, start, sorted);

    const int nrows_blocks = (NB * NV * NG) / 8;
    b_gather<<<nrows_blocks, 256, 0, stream>>>(features, pixarr, start, sorted,
                                               Wlin, blin, At, out);
}